// Round 12
// baseline (235.510 us; speedup 1.0000x reference)
//
#include <hip/hip_runtime.h>
#include <cstdint>

#define K_NE 16
constexpr int B = 8, N = 2048, F = 128;
constexpr size_t NSEND = (size_t)B * N;                 // 16384 sender rows
constexpr size_t EDGE_FLOATS = NSEND * K_NE * 256;      // 67,108,864
constexpr size_t SEND_FLOATS = (size_t)B * N * N;       // 33,554,432

typedef _Float16 half8 __attribute__((ext_vector_type(8)));
typedef _Float16 half4 __attribute__((ext_vector_type(4)));
typedef float floatx4 __attribute__((ext_vector_type(4)));

#define SCALE 2048.0f                    // exact power of 2
#define INV_SC2 2.384185791015625e-07f   // 2^-22, exact
#define F16_MIN_NORM 6.103515625e-05f    // 2^-14

// ---------------- K0: row norms (one wave per 128-float row) ----------------
__global__ __launch_bounds__(256) void norms_kernel(const float* __restrict__ X,
                                                    float* __restrict__ out) {
    int tid = blockIdx.x * 256 + threadIdx.x;
    int w = tid >> 6, lane = tid & 63;
    const float2 v = ((const float2*)(X + (size_t)w * F))[lane];
    float s = v.x * v.x + v.y * v.y;
    #pragma unroll
    for (int off = 32; off; off >>= 1) s += __shfl_xor(s, off);
    if (lane == 0) out[w] = s;
}

// ---------------- K0b: f32 -> scaled (f16 hi, f16 lo), denormal-free --------
// a' = 2048*a (exact).  h = f16(a') FTZ'd; l = f16(a'-h) FTZ'd.  All MFMA
// inputs are normal f16; the 2^22 product scale is undone exactly in the
// epilogue, so scores are bit-identical to the unscaled r11 version (which
// passed absmax 0) up to ~1e-7 FTZ dust (selection tolerates ~1e-4).
__global__ __launch_bounds__(256) void convert_kernel(const float* __restrict__ S,
                                                      const float* __restrict__ Rv,
                                                      _Float16* __restrict__ SH,
                                                      _Float16* __restrict__ SL,
                                                      _Float16* __restrict__ RH,
                                                      _Float16* __restrict__ RL) {
    const int i = blockIdx.x * 256 + threadIdx.x;   // quad index
    const int half_n = (int)(NSEND * F / 4);        // 524288 quads per matrix
    const float* X; _Float16 *H, *L; int q;
    if (i < half_n) { X = S;  H = SH; L = SL; q = i; }
    else            { X = Rv; H = RH; L = RL; q = i - half_n; }
    const float4 v = ((const float4*)X)[q];
    float a[4] = {v.x * SCALE, v.y * SCALE, v.z * SCALE, v.w * SCALE};
    half4 h, l;
    #pragma unroll
    for (int c = 0; c < 4; ++c) {
        _Float16 hh = (_Float16)a[c];
        if (fabsf((float)hh) < F16_MIN_NORM) hh = (_Float16)0.0f;
        float lf = a[c] - (float)hh;
        _Float16 ll = (_Float16)lf;
        if (fabsf((float)ll) < F16_MIN_NORM) ll = (_Float16)0.0f;
        ((_Float16*)&h)[c] = hh;
        ((_Float16*)&l)[c] = ll;
    }
    *(half4*)(H + 4 * (size_t)q) = h;
    *(half4*)(L + 4 * (size_t)q) = l;
}

// ---------------- K1: MFMA score matrix  dist = |x2+y2-2*dot| ---------------
// 128x128 block tile, 8 waves of 64x32 (4x2 fragments) -> 32 AGPR + ~90 VGPR
// => 3-4 waves/SIMD (r11's 4x4 tile was 184 unified regs -> 2 waves/SIMD).
// mfma_f32_16x16x32_f16, scaled hi/lo split: acc += ah*bh + ah*bl + al*bh,
// all inputs normal f16; epilogue unscales by exact 2^-22.
__global__ __launch_bounds__(512) void score_mfma_kernel(
        const _Float16* __restrict__ SH, const _Float16* __restrict__ SL,
        const _Float16* __restrict__ RH, const _Float16* __restrict__ RL,
        const float* __restrict__ x2, const float* __restrict__ y2,
        float* __restrict__ scores) {
    const int bx = blockIdx.x, by = blockIdx.y, bz = blockIdx.z;
    const int t = threadIdx.x, lane = t & 63, wv = t >> 6;   // wv 0..7
    const int row0 = by * 128 + (wv >> 2) * 64;   // batch-local sender base
    const int col0 = bx * 128 + (wv & 3) * 32;    // batch-local receiver base
    const int lr = lane & 15, lk = (lane >> 4) * 8;

    const size_t sOff = ((size_t)(bz * N + row0 + lr)) * F + lk;
    const size_t rOff = ((size_t)(bz * N + col0 + lr)) * F + lk;
    const _Float16* pSH = SH + sOff;
    const _Float16* pSL = SL + sOff;
    const _Float16* pRH = RH + rOff;
    const _Float16* pRL = RL + rOff;

    floatx4 acc[4][2] = {};

    #pragma unroll 1
    for (int ks = 0; ks < 4; ++ks) {
        const int ko = ks * 32;
        half8 ah[4], al[4], bh[2], bl[2];
        #pragma unroll
        for (int i = 0; i < 4; ++i) {
            ah[i] = *(const half8*)(pSH + (size_t)i * 16 * F + ko);
            al[i] = *(const half8*)(pSL + (size_t)i * 16 * F + ko);
        }
        #pragma unroll
        for (int j = 0; j < 2; ++j) {
            bh[j] = *(const half8*)(pRH + (size_t)j * 16 * F + ko);
            bl[j] = *(const half8*)(pRL + (size_t)j * 16 * F + ko);
        }
        #pragma unroll
        for (int j = 0; j < 2; ++j)
            #pragma unroll
            for (int i = 0; i < 4; ++i) {
                acc[i][j] = __builtin_amdgcn_mfma_f32_16x16x32_f16(ah[i], bh[j], acc[i][j], 0, 0, 0);
                acc[i][j] = __builtin_amdgcn_mfma_f32_16x16x32_f16(ah[i], bl[j], acc[i][j], 0, 0, 0);
                acc[i][j] = __builtin_amdgcn_mfma_f32_16x16x32_f16(al[i], bh[j], acc[i][j], 0, 0, 0);
            }
    }

    float* outb = scores + (size_t)bz * N * N;
    const float* x2b = x2 + (size_t)bz * N;
    const float* y2b = y2 + (size_t)bz * N;
    #pragma unroll
    for (int j = 0; j < 2; ++j) {
        const int col = col0 + j * 16 + lr;
        const float yv = y2b[col];
        #pragma unroll
        for (int i = 0; i < 4; ++i) {
            #pragma unroll
            for (int r = 0; r < 4; ++r) {
                const int row = row0 + i * 16 + (lane >> 4) * 4 + r;
                const float d = acc[i][j][r] * INV_SC2;   // exact unscale
                outb[(size_t)row * N + col] = fabsf((-2.0f * d + x2b[row]) + yv);
            }
        }
    }
}

// ------- K2: fused top-16 + connectivity row + edge rows (r6 version) -------
__global__ __launch_bounds__(256) void topk_fused_kernel(const float* __restrict__ S,
                                                         const float* __restrict__ Rv,
                                                         float* __restrict__ scores,
                                                         float* __restrict__ edges_out) {
    __shared__ uint32_t rowbuf[4][N];     // 32 KB, lane-private slices
    const int t = threadIdx.x;
    const int lane = t & 63;
    const int w = t >> 6;
    const int g = blockIdx.x * 4 + w;     // global sender id 0..16383
    const int bz = g >> 11;               // batch
    uint32_t* lds = rowbuf[w];
    float* srowp = scores + (size_t)g * N;
    const uint4* sr = (const uint4*)srowp;

    uint32_t mk = 0xFFFFFFFFu, mi = 0;
    #pragma unroll
    for (int jj = 0; jj < 8; ++jj) {
        uint4 u = sr[jj * 64 + lane];
        *(uint4*)(&lds[jj * 256 + lane * 4]) = u;
        const uint32_t base = (uint32_t)(jj * 256 + lane * 4);
        if (u.x < mk) { mk = u.x; mi = base; }
        if (u.y < mk) { mk = u.y; mi = base + 1; }
        if (u.z < mk) { mk = u.z; mi = base + 2; }
        if (u.w < mk) { mk = u.w; mi = base + 3; }
    }

    int ixs[16];
    #pragma unroll
    for (int it = 0; it < 16; ++it) {
        const uint32_t ck = mk, ci = mi;
        uint32_t gk = mk, gi = mi;
        #pragma unroll
        for (int off = 32; off; off >>= 1) {
            uint32_t ok = (uint32_t)__shfl_xor((int)gk, off);
            uint32_t oi = (uint32_t)__shfl_xor((int)gi, off);
            if (ok < gk || (ok == gk && oi < gi)) { gk = ok; gi = oi; }
        }
        ixs[it] = (int)gi;
        if (ck == gk && ci == gi) {       // unique owner lane
            lds[gi] = 0xFFFFFFFFu;        // delete
            mk = 0xFFFFFFFFu; mi = 0;     // rescan own 32 slots
            #pragma unroll
            for (int jj = 0; jj < 8; ++jj) {
                uint4 u = *(const uint4*)(&lds[jj * 256 + lane * 4]);
                const uint32_t base = (uint32_t)(jj * 256 + lane * 4);
                if (u.x < mk) { mk = u.x; mi = base; }
                if (u.y < mk) { mk = u.y; mi = base + 1; }
                if (u.z < mk) { mk = u.z; mi = base + 2; }
                if (u.w < mk) { mk = u.w; mi = base + 3; }
            }
        }
    }

    int rank[16];
    #pragma unroll
    for (int e = 0; e < 16; ++e) {
        int r = 0;
        #pragma unroll
        for (int f = 0; f < 16; ++f) r += (ixs[f] < ixs[e]) ? 1 : 0;
        rank[e] = r;
    }

    uint32_t mask = 0;
    #pragma unroll
    for (int e = 0; e < 16; ++e) {
        const int ix = ixs[e];
        const int lane_t = (ix >> 2) & 63;
        const int bitpos = ((ix >> 8) << 2) | (ix & 3);
        if (lane == lane_t) mask |= (1u << bitpos);
    }
    #pragma unroll
    for (int j = 0; j < 8; ++j) {
        float4 v;
        v.x = (mask >> (j * 4 + 0)) & 1u ? 1.f : 0.f;
        v.y = (mask >> (j * 4 + 1)) & 1u ? 1.f : 0.f;
        v.z = (mask >> (j * 4 + 2)) & 1u ? 1.f : 0.f;
        v.w = (mask >> (j * 4 + 3)) & 1u ? 1.f : 0.f;
        *(float4*)(srowp + j * 256 + lane * 4) = v;
    }

    const float* srow = S + (size_t)g * F;
    const float* rb = Rv + (size_t)bz * N * F;
    float4 vs = {0.f, 0.f, 0.f, 0.f};
    if (lane < 32) vs = *(const float4*)(srow + lane * 4);
    #pragma unroll
    for (int e = 0; e < 16; ++e) {
        float4 v = vs;
        if (lane >= 32)
            v = *(const float4*)(rb + (size_t)ixs[e] * F + (lane - 32) * 4);
        *(float4*)(edges_out + ((size_t)g * K_NE + rank[e]) * 256 + lane * 4) = v;
    }
}

extern "C" void kernel_launch(void* const* d_in, const int* in_sizes, int n_in,
                              void* d_out, int out_size, void* d_ws, size_t ws_size,
                              hipStream_t stream) {
    (void)in_sizes; (void)n_in; (void)out_size; (void)ws_size;
    const float* recv = (const float*)d_in[0];
    const float* send = (const float*)d_in[1];
    float* out = (float*)d_out;
    float* sender_mat = out + EDGE_FLOATS;       // score scratch, then conn matrix
    float* x2 = (float*)((char*)d_ws + (262144u * 4));
    float* y2 = x2 + NSEND;

    // f16 hi/lo staging lives in the edges region (dead until topk_fused).
    _Float16* SH = (_Float16*)out;
    _Float16* SL = SH + NSEND * F;
    _Float16* RH = SL + NSEND * F;
    _Float16* RL = RH + NSEND * F;               // total 16.8 MB << 256 MB

    norms_kernel<<<4096, 256, 0, stream>>>(send, x2);
    norms_kernel<<<4096, 256, 0, stream>>>(recv, y2);
    convert_kernel<<<4096, 256, 0, stream>>>(send, recv, SH, SL, RH, RL);
    dim3 g1(16, 16, 8);
    score_mfma_kernel<<<g1, 512, 0, stream>>>(SH, SL, RH, RL, x2, y2, sender_mat);
    topk_fused_kernel<<<4096, 256, 0, stream>>>(send, recv, sender_mat, out);
}

// Round 13
// 222.648 us; speedup vs baseline: 1.0578x; 1.0578x over previous
//
#include <hip/hip_runtime.h>
#include <cstdint>

#define K_NE 16
constexpr int B = 8, N = 2048, F = 128;
constexpr size_t NSEND = (size_t)B * N;                 // 16384 sender rows
constexpr size_t EDGE_FLOATS = NSEND * K_NE * 256;      // 67,108,864
constexpr size_t SEND_FLOATS = (size_t)B * N * N;       // 33,554,432

typedef _Float16 half8 __attribute__((ext_vector_type(8)));
typedef _Float16 half4 __attribute__((ext_vector_type(4)));
typedef float floatx4 __attribute__((ext_vector_type(4)));

#define SCALE 2048.0f                    // exact power of 2
#define INV_SC2 2.384185791015625e-07f   // 2^-22, exact
#define F16_MIN_NORM 6.103515625e-05f    // 2^-14

// ---------------- K0: row norms (one wave per 128-float row) ----------------
__global__ __launch_bounds__(256) void norms_kernel(const float* __restrict__ X,
                                                    float* __restrict__ out) {
    int tid = blockIdx.x * 256 + threadIdx.x;
    int w = tid >> 6, lane = tid & 63;
    const float2 v = ((const float2*)(X + (size_t)w * F))[lane];
    float s = v.x * v.x + v.y * v.y;
    #pragma unroll
    for (int off = 32; off; off >>= 1) s += __shfl_xor(s, off);
    if (lane == 0) out[w] = s;
}

// ---------------- K0b: f32 -> scaled (f16 hi, f16 lo), denormal-free --------
// (r12 version, validated absmax 0; kills the f16-denormal MFMA slow path)
__global__ __launch_bounds__(256) void convert_kernel(const float* __restrict__ S,
                                                      const float* __restrict__ Rv,
                                                      _Float16* __restrict__ SH,
                                                      _Float16* __restrict__ SL,
                                                      _Float16* __restrict__ RH,
                                                      _Float16* __restrict__ RL) {
    const int i = blockIdx.x * 256 + threadIdx.x;   // quad index
    const int half_n = (int)(NSEND * F / 4);        // 524288 quads per matrix
    const float* X; _Float16 *H, *L; int q;
    if (i < half_n) { X = S;  H = SH; L = SL; q = i; }
    else            { X = Rv; H = RH; L = RL; q = i - half_n; }
    const float4 v = ((const float4*)X)[q];
    float a[4] = {v.x * SCALE, v.y * SCALE, v.z * SCALE, v.w * SCALE};
    half4 h, l;
    #pragma unroll
    for (int c = 0; c < 4; ++c) {
        _Float16 hh = (_Float16)a[c];
        if (fabsf((float)hh) < F16_MIN_NORM) hh = (_Float16)0.0f;
        float lf = a[c] - (float)hh;
        _Float16 ll = (_Float16)lf;
        if (fabsf((float)ll) < F16_MIN_NORM) ll = (_Float16)0.0f;
        ((_Float16*)&h)[c] = hh;
        ((_Float16*)&l)[c] = ll;
    }
    *(half4*)(H + 4 * (size_t)q) = h;
    *(half4*)(L + 4 * (size_t)q) = l;
}

// ---------------- K1: MFMA score matrix  dist = |x2+y2-2*dot| ---------------
// r11 structure (128x128 block, 4 waves of 64x64, acc[4][4]) + r12 scaling,
// with the ks loop FULLY UNROLLED (was `unroll 1`, which serialized
// {16 L2-latency loads} -> {48 MFMAs} per ks with no cross-iteration
// overlap). Full unroll lets the scheduler hoist next-ks loads under the
// current MFMA block. Each acc chain's MFMA sequence is fixed by data deps
// -> bit-identical scores to r12.
__global__ __launch_bounds__(256) void score_mfma_kernel(
        const _Float16* __restrict__ SH, const _Float16* __restrict__ SL,
        const _Float16* __restrict__ RH, const _Float16* __restrict__ RL,
        const float* __restrict__ x2, const float* __restrict__ y2,
        float* __restrict__ scores) {
    const int bx = blockIdx.x, by = blockIdx.y, bz = blockIdx.z;
    const int t = threadIdx.x, lane = t & 63, wv = t >> 6;
    const int row0 = by * 128 + (wv >> 1) * 64;   // batch-local sender base
    const int col0 = bx * 128 + (wv & 1) * 64;    // batch-local receiver base
    const int lr = lane & 15, lk = (lane >> 4) * 8;

    const size_t sOff = ((size_t)(bz * N + row0 + lr)) * F + lk;
    const size_t rOff = ((size_t)(bz * N + col0 + lr)) * F + lk;
    const _Float16* pSH = SH + sOff;
    const _Float16* pSL = SL + sOff;
    const _Float16* pRH = RH + rOff;
    const _Float16* pRL = RL + rOff;

    floatx4 acc[4][4] = {};

    #pragma unroll
    for (int ks = 0; ks < 4; ++ks) {
        const int ko = ks * 32;
        half8 ah[4], al[4];
        #pragma unroll
        for (int i = 0; i < 4; ++i) {
            ah[i] = *(const half8*)(pSH + (size_t)i * 16 * F + ko);
            al[i] = *(const half8*)(pSL + (size_t)i * 16 * F + ko);
        }
        #pragma unroll
        for (int j = 0; j < 4; ++j) {
            const half8 bh = *(const half8*)(pRH + (size_t)j * 16 * F + ko);
            const half8 bl = *(const half8*)(pRL + (size_t)j * 16 * F + ko);
            #pragma unroll
            for (int i = 0; i < 4; ++i) {
                acc[i][j] = __builtin_amdgcn_mfma_f32_16x16x32_f16(ah[i], bh, acc[i][j], 0, 0, 0);
                acc[i][j] = __builtin_amdgcn_mfma_f32_16x16x32_f16(ah[i], bl, acc[i][j], 0, 0, 0);
                acc[i][j] = __builtin_amdgcn_mfma_f32_16x16x32_f16(al[i], bh, acc[i][j], 0, 0, 0);
            }
        }
    }

    float* outb = scores + (size_t)bz * N * N;
    const float* x2b = x2 + (size_t)bz * N;
    const float* y2b = y2 + (size_t)bz * N;
    #pragma unroll
    for (int j = 0; j < 4; ++j) {
        const int col = col0 + j * 16 + lr;
        const float yv = y2b[col];
        #pragma unroll
        for (int i = 0; i < 4; ++i) {
            #pragma unroll
            for (int r = 0; r < 4; ++r) {
                const int row = row0 + i * 16 + (lane >> 4) * 4 + r;
                const float d = acc[i][j][r] * INV_SC2;   // exact unscale
                outb[(size_t)row * N + col] = fabsf((-2.0f * d + x2b[row]) + yv);
            }
        }
    }
}

// ------- K2: fused top-16 + connectivity row + edge rows (frozen r6) --------
__global__ __launch_bounds__(256) void topk_fused_kernel(const float* __restrict__ S,
                                                         const float* __restrict__ Rv,
                                                         float* __restrict__ scores,
                                                         float* __restrict__ edges_out) {
    __shared__ uint32_t rowbuf[4][N];     // 32 KB, lane-private slices
    const int t = threadIdx.x;
    const int lane = t & 63;
    const int w = t >> 6;
    const int g = blockIdx.x * 4 + w;     // global sender id 0..16383
    const int bz = g >> 11;               // batch
    uint32_t* lds = rowbuf[w];
    float* srowp = scores + (size_t)g * N;
    const uint4* sr = (const uint4*)srowp;

    uint32_t mk = 0xFFFFFFFFu, mi = 0;
    #pragma unroll
    for (int jj = 0; jj < 8; ++jj) {
        uint4 u = sr[jj * 64 + lane];
        *(uint4*)(&lds[jj * 256 + lane * 4]) = u;
        const uint32_t base = (uint32_t)(jj * 256 + lane * 4);
        if (u.x < mk) { mk = u.x; mi = base; }
        if (u.y < mk) { mk = u.y; mi = base + 1; }
        if (u.z < mk) { mk = u.z; mi = base + 2; }
        if (u.w < mk) { mk = u.w; mi = base + 3; }
    }

    int ixs[16];
    #pragma unroll
    for (int it = 0; it < 16; ++it) {
        const uint32_t ck = mk, ci = mi;
        uint32_t gk = mk, gi = mi;
        #pragma unroll
        for (int off = 32; off; off >>= 1) {
            uint32_t ok = (uint32_t)__shfl_xor((int)gk, off);
            uint32_t oi = (uint32_t)__shfl_xor((int)gi, off);
            if (ok < gk || (ok == gk && oi < gi)) { gk = ok; gi = oi; }
        }
        ixs[it] = (int)gi;
        if (ck == gk && ci == gi) {       // unique owner lane
            lds[gi] = 0xFFFFFFFFu;        // delete
            mk = 0xFFFFFFFFu; mi = 0;     // rescan own 32 slots
            #pragma unroll
            for (int jj = 0; jj < 8; ++jj) {
                uint4 u = *(const uint4*)(&lds[jj * 256 + lane * 4]);
                const uint32_t base = (uint32_t)(jj * 256 + lane * 4);
                if (u.x < mk) { mk = u.x; mi = base; }
                if (u.y < mk) { mk = u.y; mi = base + 1; }
                if (u.z < mk) { mk = u.z; mi = base + 2; }
                if (u.w < mk) { mk = u.w; mi = base + 3; }
            }
        }
    }

    int rank[16];
    #pragma unroll
    for (int e = 0; e < 16; ++e) {
        int r = 0;
        #pragma unroll
        for (int f = 0; f < 16; ++f) r += (ixs[f] < ixs[e]) ? 1 : 0;
        rank[e] = r;
    }

    uint32_t mask = 0;
    #pragma unroll
    for (int e = 0; e < 16; ++e) {
        const int ix = ixs[e];
        const int lane_t = (ix >> 2) & 63;
        const int bitpos = ((ix >> 8) << 2) | (ix & 3);
        if (lane == lane_t) mask |= (1u << bitpos);
    }
    #pragma unroll
    for (int j = 0; j < 8; ++j) {
        float4 v;
        v.x = (mask >> (j * 4 + 0)) & 1u ? 1.f : 0.f;
        v.y = (mask >> (j * 4 + 1)) & 1u ? 1.f : 0.f;
        v.z = (mask >> (j * 4 + 2)) & 1u ? 1.f : 0.f;
        v.w = (mask >> (j * 4 + 3)) & 1u ? 1.f : 0.f;
        *(float4*)(srowp + j * 256 + lane * 4) = v;
    }

    const float* srow = S + (size_t)g * F;
    const float* rb = Rv + (size_t)bz * N * F;
    float4 vs = {0.f, 0.f, 0.f, 0.f};
    if (lane < 32) vs = *(const float4*)(srow + lane * 4);
    #pragma unroll
    for (int e = 0; e < 16; ++e) {
        float4 v = vs;
        if (lane >= 32)
            v = *(const float4*)(rb + (size_t)ixs[e] * F + (lane - 32) * 4);
        *(float4*)(edges_out + ((size_t)g * K_NE + rank[e]) * 256 + lane * 4) = v;
    }
}

extern "C" void kernel_launch(void* const* d_in, const int* in_sizes, int n_in,
                              void* d_out, int out_size, void* d_ws, size_t ws_size,
                              hipStream_t stream) {
    (void)in_sizes; (void)n_in; (void)out_size; (void)ws_size;
    const float* recv = (const float*)d_in[0];
    const float* send = (const float*)d_in[1];
    float* out = (float*)d_out;
    float* sender_mat = out + EDGE_FLOATS;       // score scratch, then conn matrix
    float* x2 = (float*)((char*)d_ws + (262144u * 4));
    float* y2 = x2 + NSEND;

    // f16 hi/lo staging lives in the edges region (dead until topk_fused).
    _Float16* SH = (_Float16*)out;
    _Float16* SL = SH + NSEND * F;
    _Float16* RH = SL + NSEND * F;
    _Float16* RL = RH + NSEND * F;               // total 16.8 MB << 256 MB

    norms_kernel<<<4096, 256, 0, stream>>>(send, x2);
    norms_kernel<<<4096, 256, 0, stream>>>(recv, y2);
    convert_kernel<<<4096, 256, 0, stream>>>(send, recv, SH, SL, RH, RL);
    dim3 g1(16, 16, 8);
    score_mfma_kernel<<<g1, 256, 0, stream>>>(SH, SL, RH, RL, x2, y2, sender_mat);
    topk_fused_kernel<<<4096, 256, 0, stream>>>(send, recv, sender_mat, out);
}

// Round 14
// 197.463 us; speedup vs baseline: 1.1927x; 1.1275x over previous
//
#include <hip/hip_runtime.h>
#include <cstdint>

#define K_NE 16
constexpr int B = 8, N = 2048, F = 128;
constexpr size_t NSEND = (size_t)B * N;                 // 16384 sender rows
constexpr size_t EDGE_FLOATS = NSEND * K_NE * 256;      // 67,108,864
constexpr size_t SEND_FLOATS = (size_t)B * N * N;       // 33,554,432

typedef _Float16 half8 __attribute__((ext_vector_type(8)));
typedef _Float16 half4 __attribute__((ext_vector_type(4)));
typedef float floatx4 __attribute__((ext_vector_type(4)));

#define SCALE 2048.0f                    // exact power of 2
#define INV_SC2 2.384185791015625e-07f   // 2^-22, exact
#define F16_MIN_NORM 6.103515625e-05f    // 2^-14

// ---------------- K0: row norms (one wave per 128-float row) ----------------
__global__ __launch_bounds__(256) void norms_kernel(const float* __restrict__ X,
                                                    float* __restrict__ out) {
    int tid = blockIdx.x * 256 + threadIdx.x;
    int w = tid >> 6, lane = tid & 63;
    const float2 v = ((const float2*)(X + (size_t)w * F))[lane];
    float s = v.x * v.x + v.y * v.y;
    #pragma unroll
    for (int off = 32; off; off >>= 1) s += __shfl_xor(s, off);
    if (lane == 0) out[w] = s;
}

// ---------------- K0b: f32 -> scaled (f16 hi, f16 lo), denormal-free --------
__global__ __launch_bounds__(256) void convert_kernel(const float* __restrict__ S,
                                                      const float* __restrict__ Rv,
                                                      _Float16* __restrict__ SH,
                                                      _Float16* __restrict__ SL,
                                                      _Float16* __restrict__ RH,
                                                      _Float16* __restrict__ RL) {
    const int i = blockIdx.x * 256 + threadIdx.x;   // quad index
    const int half_n = (int)(NSEND * F / 4);        // 524288 quads per matrix
    const float* X; _Float16 *H, *L; int q;
    if (i < half_n) { X = S;  H = SH; L = SL; q = i; }
    else            { X = Rv; H = RH; L = RL; q = i - half_n; }
    const float4 v = ((const float4*)X)[q];
    float a[4] = {v.x * SCALE, v.y * SCALE, v.z * SCALE, v.w * SCALE};
    half4 h, l;
    #pragma unroll
    for (int c = 0; c < 4; ++c) {
        _Float16 hh = (_Float16)a[c];
        if (fabsf((float)hh) < F16_MIN_NORM) hh = (_Float16)0.0f;
        float lf = a[c] - (float)hh;
        _Float16 ll = (_Float16)lf;
        if (fabsf((float)ll) < F16_MIN_NORM) ll = (_Float16)0.0f;
        ((_Float16*)&h)[c] = hh;
        ((_Float16*)&l)[c] = ll;
    }
    *(half4*)(H + 4 * (size_t)q) = h;
    *(half4*)(L + 4 * (size_t)q) = l;
}

// ---------------- K1: MFMA score matrix (frozen r13) ------------------------
__global__ __launch_bounds__(256) void score_mfma_kernel(
        const _Float16* __restrict__ SH, const _Float16* __restrict__ SL,
        const _Float16* __restrict__ RH, const _Float16* __restrict__ RL,
        const float* __restrict__ x2, const float* __restrict__ y2,
        float* __restrict__ scores) {
    const int bx = blockIdx.x, by = blockIdx.y, bz = blockIdx.z;
    const int t = threadIdx.x, lane = t & 63, wv = t >> 6;
    const int row0 = by * 128 + (wv >> 1) * 64;
    const int col0 = bx * 128 + (wv & 1) * 64;
    const int lr = lane & 15, lk = (lane >> 4) * 8;

    const size_t sOff = ((size_t)(bz * N + row0 + lr)) * F + lk;
    const size_t rOff = ((size_t)(bz * N + col0 + lr)) * F + lk;
    const _Float16* pSH = SH + sOff;
    const _Float16* pSL = SL + sOff;
    const _Float16* pRH = RH + rOff;
    const _Float16* pRL = RL + rOff;

    floatx4 acc[4][4] = {};

    #pragma unroll
    for (int ks = 0; ks < 4; ++ks) {
        const int ko = ks * 32;
        half8 ah[4], al[4];
        #pragma unroll
        for (int i = 0; i < 4; ++i) {
            ah[i] = *(const half8*)(pSH + (size_t)i * 16 * F + ko);
            al[i] = *(const half8*)(pSL + (size_t)i * 16 * F + ko);
        }
        #pragma unroll
        for (int j = 0; j < 4; ++j) {
            const half8 bh = *(const half8*)(pRH + (size_t)j * 16 * F + ko);
            const half8 bl = *(const half8*)(pRL + (size_t)j * 16 * F + ko);
            #pragma unroll
            for (int i = 0; i < 4; ++i) {
                acc[i][j] = __builtin_amdgcn_mfma_f32_16x16x32_f16(ah[i], bh, acc[i][j], 0, 0, 0);
                acc[i][j] = __builtin_amdgcn_mfma_f32_16x16x32_f16(ah[i], bl, acc[i][j], 0, 0, 0);
                acc[i][j] = __builtin_amdgcn_mfma_f32_16x16x32_f16(al[i], bh, acc[i][j], 0, 0, 0);
            }
        }
    }

    float* outb = scores + (size_t)bz * N * N;
    const float* x2b = x2 + (size_t)bz * N;
    const float* y2b = y2 + (size_t)bz * N;
    #pragma unroll
    for (int j = 0; j < 4; ++j) {
        const int col = col0 + j * 16 + lr;
        const float yv = y2b[col];
        #pragma unroll
        for (int i = 0; i < 4; ++i) {
            #pragma unroll
            for (int r = 0; r < 4; ++r) {
                const int row = row0 + i * 16 + (lane >> 4) * 4 + r;
                const float d = acc[i][j][r] * INV_SC2;
                outb[(size_t)row * N + col] = fabsf((-2.0f * d + x2b[row]) + yv);
            }
        }
    }
}

// ------- K2: fused top-16 via threshold filter + bitonic select -------------
// T16 = 16th-smallest of the 64 lane-mins bounds the top-16 (the 16 smallest
// lane-mins are 16 distinct values, so global 16th value <= T16). Candidates
// (key <= T16, typically ~20-40) are gathered to LDS as exact f64-packed
// (key*2048+idx) and one 64-lane bitonic sort yields the lexicographic
// top-16 -- replacing 16 serialized LDS owner-rescan round-trips. cnt>64
// (tie storm) falls back to the old exact iterative extraction.
__global__ __launch_bounds__(256) void topk_fused_kernel(const float* __restrict__ S,
                                                         const float* __restrict__ Rv,
                                                         float* __restrict__ scores,
                                                         float* __restrict__ edges_out) {
    __shared__ uint32_t rowbuf[4][N];     // 32 KB, lane-private slices
    __shared__ double candbuf[4][64];     // 2 KB candidate buffers
    const int t = threadIdx.x;
    const int lane = t & 63;
    const int w = t >> 6;
    const int g = blockIdx.x * 4 + w;     // global sender id 0..16383
    const int bz = g >> 11;               // batch
    uint32_t* lds = rowbuf[w];
    double* cbuf = candbuf[w];
    float* srowp = scores + (size_t)g * N;
    const uint4* sr = (const uint4*)srowp;
    const double MAGIC = 4503599627370496.0;   // 2^52

    // ---- load row -> LDS keys; per-lane value-min ------------------------
    uint32_t mk = 0xFFFFFFFFu;
    #pragma unroll
    for (int jj = 0; jj < 8; ++jj) {
        uint4 u = sr[jj * 64 + lane];
        *(uint4*)(&lds[jj * 256 + lane * 4]) = u;
        mk = mk < u.x ? mk : u.x;
        mk = mk < u.y ? mk : u.y;
        mk = mk < u.z ? mk : u.z;
        mk = mk < u.w ? mk : u.w;
    }

    // ---- bitonic sort of lane-mins (ascending) -> T16 = sorted[15] -------
    uint32_t v = mk;
    #pragma unroll
    for (int k = 2; k <= 64; k <<= 1) {
        #pragma unroll
        for (int j = k >> 1; j >= 1; j >>= 1) {
            uint32_t o = (uint32_t)__shfl_xor((int)v, j);
            const bool take_min = (((lane & j) == 0) == ((lane & k) == 0));
            const uint32_t mn = v < o ? v : o;
            const uint32_t mx = v < o ? o : v;
            v = take_min ? mn : mx;
        }
    }
    const uint32_t T16 = (uint32_t)__shfl((int)v, 15);

    // ---- gather candidates (key <= T16) into cbuf, slot-ordered ----------
    int cnt = 0;
    #pragma unroll
    for (int jj = 0; jj < 8; ++jj) {
        const uint4 u = *(const uint4*)(&lds[jj * 256 + lane * 4]);
        #pragma unroll
        for (int c = 0; c < 4; ++c) {
            const uint32_t key = (c == 0) ? u.x : (c == 1) ? u.y : (c == 2) ? u.z : u.w;
            const bool f = key <= T16;
            const unsigned long long m = __ballot(f);
            if (f) {
                const int pos = cnt + __popcll(m & ((1ull << lane) - 1ull));
                if (pos < 64)
                    cbuf[pos] = (double)key * 2048.0 + (double)(jj * 256 + lane * 4 + c);
            }
            cnt += __popcll(m);
        }
    }

    int ixs[16];
    if (cnt <= 64) {
        // ---- f64 bitonic sort of candidates; lanes 0..15 = top-16 --------
        double d = (lane < cnt) ? cbuf[lane] : 1e300;
        #pragma unroll
        for (int k = 2; k <= 64; k <<= 1) {
            #pragma unroll
            for (int j = k >> 1; j >= 1; j >>= 1) {
                const double o = __shfl_xor(d, j);
                const bool take_min = (((lane & j) == 0) == ((lane & k) == 0));
                d = take_min ? fmin(d, o) : fmax(d, o);
            }
        }
        const int myidx = (int)(__double_as_longlong(d + MAGIC) & 2047);
        #pragma unroll
        for (int e = 0; e < 16; ++e) ixs[e] = __shfl(myidx, e);
    } else {
        // ---- fallback (tie storm): exact iterative owner-rescan ----------
        uint32_t fk = 0xFFFFFFFFu, fi = 0;
        #pragma unroll
        for (int jj = 0; jj < 8; ++jj) {
            const uint4 u = *(const uint4*)(&lds[jj * 256 + lane * 4]);
            const uint32_t base = (uint32_t)(jj * 256 + lane * 4);
            if (u.x < fk) { fk = u.x; fi = base; }
            if (u.y < fk) { fk = u.y; fi = base + 1; }
            if (u.z < fk) { fk = u.z; fi = base + 2; }
            if (u.w < fk) { fk = u.w; fi = base + 3; }
        }
        #pragma unroll
        for (int it = 0; it < 16; ++it) {
            const uint32_t ck = fk, ci = fi;
            uint32_t gk = fk, gi = fi;
            #pragma unroll
            for (int off = 32; off; off >>= 1) {
                uint32_t ok = (uint32_t)__shfl_xor((int)gk, off);
                uint32_t oi = (uint32_t)__shfl_xor((int)gi, off);
                if (ok < gk || (ok == gk && oi < gi)) { gk = ok; gi = oi; }
            }
            ixs[it] = (int)gi;
            if (ck == gk && ci == gi) {
                lds[gi] = 0xFFFFFFFFu;
                fk = 0xFFFFFFFFu; fi = 0;
                #pragma unroll
                for (int jj = 0; jj < 8; ++jj) {
                    const uint4 u = *(const uint4*)(&lds[jj * 256 + lane * 4]);
                    const uint32_t base = (uint32_t)(jj * 256 + lane * 4);
                    if (u.x < fk) { fk = u.x; fi = base; }
                    if (u.y < fk) { fk = u.y; fi = base + 1; }
                    if (u.z < fk) { fk = u.z; fi = base + 2; }
                    if (u.w < fk) { fk = u.w; fi = base + 3; }
                }
            }
        }
    }

    // ---- ranks: output slot = ascending receiver-index position -----------
    int rank[16];
    #pragma unroll
    for (int e = 0; e < 16; ++e) {
        int r = 0;
        #pragma unroll
        for (int f = 0; f < 16; ++f) r += (ixs[f] < ixs[e]) ? 1 : 0;
        rank[e] = r;
    }

    // ---- connectivity row (overwrites this wave's score row) --------------
    uint32_t mask = 0;
    #pragma unroll
    for (int e = 0; e < 16; ++e) {
        const int ix = ixs[e];
        const int lane_t = (ix >> 2) & 63;
        const int bitpos = ((ix >> 8) << 2) | (ix & 3);
        if (lane == lane_t) mask |= (1u << bitpos);
    }
    #pragma unroll
    for (int j = 0; j < 8; ++j) {
        float4 vv;
        vv.x = (mask >> (j * 4 + 0)) & 1u ? 1.f : 0.f;
        vv.y = (mask >> (j * 4 + 1)) & 1u ? 1.f : 0.f;
        vv.z = (mask >> (j * 4 + 2)) & 1u ? 1.f : 0.f;
        vv.w = (mask >> (j * 4 + 3)) & 1u ? 1.f : 0.f;
        *(float4*)(srowp + j * 256 + lane * 4) = vv;
    }

    // ---- edge rows: [sender_feat(128) | recv_feat(128)] -------------------
    const float* srow = S + (size_t)g * F;
    const float* rb = Rv + (size_t)bz * N * F;
    float4 vs = {0.f, 0.f, 0.f, 0.f};
    if (lane < 32) vs = *(const float4*)(srow + lane * 4);
    #pragma unroll
    for (int e = 0; e < 16; ++e) {
        float4 vv = vs;
        if (lane >= 32)
            vv = *(const float4*)(rb + (size_t)ixs[e] * F + (lane - 32) * 4);
        *(float4*)(edges_out + ((size_t)g * K_NE + rank[e]) * 256 + lane * 4) = vv;
    }
}

extern "C" void kernel_launch(void* const* d_in, const int* in_sizes, int n_in,
                              void* d_out, int out_size, void* d_ws, size_t ws_size,
                              hipStream_t stream) {
    (void)in_sizes; (void)n_in; (void)out_size; (void)ws_size;
    const float* recv = (const float*)d_in[0];
    const float* send = (const float*)d_in[1];
    float* out = (float*)d_out;
    float* sender_mat = out + EDGE_FLOATS;       // score scratch, then conn matrix
    float* x2 = (float*)((char*)d_ws + (262144u * 4));
    float* y2 = x2 + NSEND;

    // f16 hi/lo staging lives in the edges region (dead until topk_fused).
    _Float16* SH = (_Float16*)out;
    _Float16* SL = SH + NSEND * F;
    _Float16* RH = SL + NSEND * F;
    _Float16* RL = RH + NSEND * F;               // total 16.8 MB << 256 MB

    norms_kernel<<<4096, 256, 0, stream>>>(send, x2);
    norms_kernel<<<4096, 256, 0, stream>>>(recv, y2);
    convert_kernel<<<4096, 256, 0, stream>>>(send, recv, SH, SL, RH, RL);
    dim3 g1(16, 16, 8);
    score_mfma_kernel<<<g1, 256, 0, stream>>>(SH, SL, RH, RL, x2, y2, sender_mat);
    topk_fused_kernel<<<4096, 256, 0, stream>>>(send, recv, sender_mat, out);
}